// Round 3
// baseline (139.377 us; speedup 1.0000x reference)
//
#include <hip/hip_runtime.h>

// Problem constants (from reference)
#define B_ 32
#define C_ 32
#define T_ 8192
#define N_ 256
#define P_ 6
#define TV_ (T_ - P_ + 1)   // valid conv length = 8187

// ---------------------------------------------------------------------------
// k_prep: blocks 0..255 decode one-hot -> chars[B][T] (u8 packed in u32);
//         block 256 discretizes patterns into canonical match tables:
//   xsplat[p][n]: XOR splat (req*0x01010101 if unique argmax; 0x7F7F7F7F if
//                 tied argmax -> can never match: column contributes >=2 to
//                 psum but at most 1 to conv)
//   orm[p][n]:    0x80808080 if position active, 0 if don't-care (column
//                 sum <= 0 -> contributes 0 to both psum and conv)
// Match(b,t,n) = AND_p [ don't-care OR chars[t+p]==req[p][n] ]; pad region
// (t >= TV_) matches iff all p don't-care (psum==0).
// ---------------------------------------------------------------------------
__global__ void k_prep(const float* __restrict__ inp,
                       const float* __restrict__ pat,
                       unsigned* __restrict__ chars32,
                       unsigned* __restrict__ xsplat,
                       unsigned* __restrict__ orm) {
    int bx = blockIdx.x;
    if (bx < B_ * (T_ / 1024)) {
        // ---- one-hot decode: chars[b][t] = sum_c c * input[b,c,t] ----
        int b = bx >> 3;
        int t = ((bx & 7) << 10) + (threadIdx.x << 2);
        const float* base = inp + (size_t)b * C_ * T_ + t;
        float ax = 0.f, ay = 0.f, az = 0.f, aw = 0.f;
        #pragma unroll
        for (int c = 0; c < C_; ++c) {
            float4 v = *(const float4*)(base + (size_t)c * T_);
            float fc = (float)c;
            ax += fc * v.x; ay += fc * v.y; az += fc * v.z; aw += fc * v.w;
        }
        unsigned w = ((unsigned)(ax + 0.5f))
                   | ((unsigned)(ay + 0.5f) << 8)
                   | ((unsigned)(az + 0.5f) << 16)
                   | ((unsigned)(aw + 0.5f) << 24);
        chars32[((size_t)b * T_ + t) >> 2] = w;
    } else {
        // ---- pattern discretization -> canonical tables ----
        for (int i = threadIdx.x; i < P_ * N_; i += 256) {
            int p = i / N_;
            int n = i - p * N_;
            float maxv = -3.402823466e+38f;
            float sum = 0.0f;
            unsigned mask = 0u;
            #pragma unroll
            for (int c = 0; c < C_; ++c) {
                float v = pat[((size_t)c * P_ + p) * N_ + n];
                sum += v;
                if (v > maxv) { maxv = v; mask = (1u << c); }
                else if (v == maxv) { mask |= (1u << c); }
            }
            if (!(sum > 0.0f)) mask = 0u;
            int pc = __popc(mask);
            unsigned xs, om;
            if (pc == 0) {          // column all-zero: don't-care
                xs = 0u;            om = 0u;
            } else if (pc == 1) {   // unique argmax char
                unsigned r = (unsigned)__builtin_ctz(mask);
                xs = r * 0x01010101u;  om = 0x80808080u;
            } else {                // tie: never matches
                xs = 0x7F7F7F7Fu;   om = 0x80808080u;
            }
            xsplat[i] = xs;
            orm[i]    = om;
        }
    }
}

// ---------------------------------------------------------------------------
// k_final: identical structure to the 77us round-1 kernel (grid (8,256,32),
// LDS staging of the chars chunk, ONE float4 store per thread). Only the
// match arithmetic changed: byte-SIMD equality test.
//   x = cw[p] ^ xsplat; zero byte <=> char match. (x + 0x7F7F7F7F) sets
//   bit7 of each byte iff byte != 0 (exact: all bytes < 0x80, no carry).
//   orv accumulates mismatch bits over active positions only (orm).
// ---------------------------------------------------------------------------
__global__ void __launch_bounds__(256)
k_final(const unsigned char* __restrict__ chars,
        const unsigned* __restrict__ xsplat,
        const unsigned* __restrict__ orm,
        float* __restrict__ out) {
    __shared__ unsigned s32[258];         // 1024 chars + 8 halo bytes
    int tc  = blockIdx.x;                 // 0..7
    int n   = blockIdx.y;                 // 0..255
    int b   = blockIdx.z;                 // 0..31
    int tid = threadIdx.x;
    int t0  = tc << 10;
    int tb  = t0 + (tid << 2);

    const unsigned* csrc = (const unsigned*)(chars + (size_t)b * T_ + t0);
    s32[tid] = csrc[tid];
    if (tid < 2) {
        unsigned v = 0u;
        int gt = t0 + 1024 + tid * 4;     // byte index into chars[b][*]
        if (gt < T_) v = csrc[256 + tid];
        s32[256 + tid] = v;
    }

    // Block-uniform tables (n = blockIdx.y) -> 12 hoisted scalar loads
    unsigned xs0 = xsplat[0 * N_ + n], xs1 = xsplat[1 * N_ + n], xs2 = xsplat[2 * N_ + n];
    unsigned xs3 = xsplat[3 * N_ + n], xs4 = xsplat[4 * N_ + n], xs5 = xsplat[5 * N_ + n];
    unsigned om0 = orm[0 * N_ + n], om1 = orm[1 * N_ + n], om2 = orm[2 * N_ + n];
    unsigned om3 = orm[3 * N_ + n], om4 = orm[4 * N_ + n], om5 = orm[5 * N_ + n];
    unsigned act = om0 | om1 | om2 | om3 | om4 | om5;
    float padf = (act == 0u) ? 1.0f : 0.0f;   // psum==0: pad region matches

    __syncthreads();

    unsigned w0 = s32[tid], w1 = s32[tid + 1], w2 = s32[tid + 2];
    unsigned cw0 = w0;
    unsigned cw1 = __builtin_amdgcn_alignbyte(w1, w0, 1);
    unsigned cw2 = __builtin_amdgcn_alignbyte(w1, w0, 2);
    unsigned cw3 = __builtin_amdgcn_alignbyte(w1, w0, 3);
    unsigned cw4 = w1;
    unsigned cw5 = __builtin_amdgcn_alignbyte(w2, w1, 1);

    unsigned orv;
    orv  = ((cw0 ^ xs0) + 0x7F7F7F7FU) & om0;
    orv |= ((cw1 ^ xs1) + 0x7F7F7F7FU) & om1;   // v_and_or_b32
    orv |= ((cw2 ^ xs2) + 0x7F7F7F7FU) & om2;
    orv |= ((cw3 ^ xs3) + 0x7F7F7F7FU) & om3;
    orv |= ((cw4 ^ xs4) + 0x7F7F7F7FU) & om4;
    orv |= ((cw5 ^ xs5) + 0x7F7F7F7FU) & om5;

    float res[4];
    #pragma unroll
    for (int j = 0; j < 4; ++j)
        res[j] = (float)(((orv >> (8 * j + 7)) & 1u) ^ 1u);

    if (tb + 3 >= TV_) {                  // only the last chunk's tail lanes
        #pragma unroll
        for (int j = 0; j < 4; ++j)
            if (tb + j >= TV_) res[j] = padf;
    }

    float4 r; r.x = res[0]; r.y = res[1]; r.z = res[2]; r.w = res[3];
    *(float4*)(out + ((size_t)(b * N_ + n)) * T_ + tb) = r;
}

// ---------------------------------------------------------------------------
extern "C" void kernel_launch(void* const* d_in, const int* in_sizes, int n_in,
                              void* d_out, int out_size, void* d_ws, size_t ws_size,
                              hipStream_t stream) {
    const float* input_   = (const float*)d_in[0];   // (B,C,T,1) one-hot fp32
    const float* patterns = (const float*)d_in[1];   // (C,P,1,N) fp32
    float* out = (float*)d_out;                      // (B,N,T,1) fp32

    // ws layout: [0,6144) xsplat; [6144,12288) orm; [16384, 16384+256K) chars
    unsigned* xsplat  = (unsigned*)d_ws;
    unsigned* orm     = (unsigned*)d_ws + P_ * N_;
    unsigned char* chars = (unsigned char*)d_ws + 16384;

    hipLaunchKernelGGL(k_prep, dim3(B_ * (T_ / 1024) + 1), dim3(256), 0, stream,
                       input_, patterns, (unsigned*)chars, xsplat, orm);
    hipLaunchKernelGGL(k_final, dim3(T_ / 1024, N_, B_), dim3(256), 0, stream,
                       chars, xsplat, orm, out);
}

// Round 4
// 79.634 us; speedup vs baseline: 1.7502x; 1.7502x over previous
//
#include <hip/hip_runtime.h>

// Problem constants (from reference)
#define B_ 32
#define C_ 32
#define T_ 8192
#define N_ 256
#define P_ 6
#define TV_ (T_ - P_ + 1)   // valid conv length = 8187

// ---------------------------------------------------------------------------
// Kernel 0: discretize patterns -> per-(p,n) 32-bit char bitmask.
// (verbatim round-1 kernel: 77us total known-good scaffolding)
// ---------------------------------------------------------------------------
__global__ void k_disc(const float* __restrict__ pat, unsigned* __restrict__ masks) {
    int tid = blockIdx.x * blockDim.x + threadIdx.x;
    if (tid >= P_ * N_) return;
    int p = tid / N_;
    int n = tid - p * N_;
    float maxv = -3.402823466e+38f;
    float sum = 0.0f;
    unsigned mask = 0u;
    #pragma unroll
    for (int c = 0; c < C_; ++c) {
        float v = pat[((size_t)c * P_ + p) * N_ + n];
        sum += v;
        if (v > maxv) { maxv = v; mask = (1u << c); }
        else if (v == maxv) { mask |= (1u << c); }
    }
    if (!(sum > 0.0f)) mask = 0u;
    masks[p * N_ + n] = mask;
}

// ---------------------------------------------------------------------------
// Kernel 1: decode one-hot input (B,C,T,1) -> chars[B][T] (u8 packed in u32).
// (verbatim round-1 kernel)
// ---------------------------------------------------------------------------
__global__ void k_chars(const float* __restrict__ inp, unsigned* __restrict__ chars32) {
    int bx = blockIdx.x;                  // [0, B * T/1024)
    int b  = bx >> 3;                     // T/1024 = 8 chunks per batch
    int t  = ((bx & 7) << 10) + (threadIdx.x << 2);
    const float* base = inp + (size_t)b * C_ * T_ + t;
    float ax = 0.f, ay = 0.f, az = 0.f, aw = 0.f;
    #pragma unroll
    for (int c = 0; c < C_; ++c) {
        float4 v = *(const float4*)(base + (size_t)c * T_);
        float fc = (float)c;
        ax += fc * v.x; ay += fc * v.y; az += fc * v.z; aw += fc * v.w;
    }
    unsigned w = ((unsigned)(ax + 0.5f))
               | ((unsigned)(ay + 0.5f) << 8)
               | ((unsigned)(az + 0.5f) << 16)
               | ((unsigned)(aw + 0.5f) << 24);
    chars32[((size_t)b * T_ + t) >> 2] = w;
}

// ---------------------------------------------------------------------------
// Kernel 2: round-1 scaffolding (grid (8,256,32), LDS chars staging, 6 s_loads
// of masks, one float4 store/thread, NO launch_bounds). ONLY the inner match
// math changed vs round 1: byte-SIMD equality test.
//   Per (p,n): pc=popc(mask): 0 -> don't-care (om=0); 1 -> must equal req
//   (xs=req*0x01010101); >=2 -> never matches (xs=0x7F7F7F7F: no char byte
//   <0x80 can xor to zero... bytes are 0..31, 0x7F works).
//   x = cw^xs; (x + 0x7F7F7F7F) has bit7-of-byte set iff byte!=0 (exact,
//   no inter-byte carry since all bytes < 0x80). orv accumulates over active p.
// All table math is blockIdx-uniform -> scalar unit, amortized over 256 thr.
// ---------------------------------------------------------------------------
__global__ void k_final(const unsigned char* __restrict__ chars,
                        const unsigned* __restrict__ masks,
                        float* __restrict__ out) {
    __shared__ unsigned s32[258];         // 1024 chars + 8 halo bytes
    int tc  = blockIdx.x;                 // 0..7
    int n   = blockIdx.y;                 // 0..255
    int b   = blockIdx.z;                 // 0..31
    int tid = threadIdx.x;
    int t0  = tc << 10;
    int tb  = t0 + (tid << 2);

    const unsigned* csrc = (const unsigned*)(chars + (size_t)b * T_ + t0);
    s32[tid] = csrc[tid];
    if (tid < 2) {
        unsigned v = 0u;
        int gt = t0 + 1024 + tid * 4;     // byte index into chars[b][*]
        if (gt < T_) v = csrc[256 + tid];
        s32[256 + tid] = v;
    }

    // Block-uniform (n from blockIdx) -> 6 scalar loads, same as round 1
    unsigned m0 = masks[0 * N_ + n], m1 = masks[1 * N_ + n], m2 = masks[2 * N_ + n];
    unsigned m3 = masks[3 * N_ + n], m4 = masks[4 * N_ + n], m5 = masks[5 * N_ + n];

    // Derive byte-SIMD constants in uniform code (SALU), no memory tables.
    #define MKTAB(m, xs, om)                                                  \
        {                                                                     \
            int pc = __popc(m);                                               \
            unsigned req = (unsigned)(__ffs(m) - 1);                          \
            xs = (pc == 1) ? req * 0x01010101u : 0x7F7F7F7Fu;                 \
            om = (pc == 0) ? 0u : 0x80808080u;                                \
        }
    unsigned xs0, xs1, xs2, xs3, xs4, xs5, om0, om1, om2, om3, om4, om5;
    MKTAB(m0, xs0, om0) MKTAB(m1, xs1, om1) MKTAB(m2, xs2, om2)
    MKTAB(m3, xs3, om3) MKTAB(m4, xs4, om4) MKTAB(m5, xs5, om5)
    #undef MKTAB
    unsigned act = om0 | om1 | om2 | om3 | om4 | om5;
    float padf = (act == 0u) ? 1.0f : 0.0f;   // psum==0: pad region matches

    __syncthreads();

    unsigned w0 = s32[tid], w1 = s32[tid + 1], w2 = s32[tid + 2];
    unsigned cw0 = w0;
    unsigned cw1 = __builtin_amdgcn_alignbyte(w1, w0, 1);
    unsigned cw2 = __builtin_amdgcn_alignbyte(w1, w0, 2);
    unsigned cw3 = __builtin_amdgcn_alignbyte(w1, w0, 3);
    unsigned cw4 = w1;
    unsigned cw5 = __builtin_amdgcn_alignbyte(w2, w1, 1);

    unsigned orv;
    orv  = ((cw0 ^ xs0) + 0x7F7F7F7FU) & om0;
    orv |= ((cw1 ^ xs1) + 0x7F7F7F7FU) & om1;   // v_and_or_b32
    orv |= ((cw2 ^ xs2) + 0x7F7F7F7FU) & om2;
    orv |= ((cw3 ^ xs3) + 0x7F7F7F7FU) & om3;
    orv |= ((cw4 ^ xs4) + 0x7F7F7F7FU) & om4;
    orv |= ((cw5 ^ xs5) + 0x7F7F7F7FU) & om5;

    float res[4];
    #pragma unroll
    for (int j = 0; j < 4; ++j)
        res[j] = (orv & (0x80u << (8 * j))) ? 0.0f : 1.0f;

    if (tc == 7) {                        // scalar branch: only last t-chunk
        #pragma unroll
        for (int j = 0; j < 4; ++j)
            if (tb + j >= TV_) res[j] = padf;
    }

    float4 r; r.x = res[0]; r.y = res[1]; r.z = res[2]; r.w = res[3];
    *(float4*)(out + ((size_t)(b * N_ + n)) * T_ + tb) = r;
}

// ---------------------------------------------------------------------------
extern "C" void kernel_launch(void* const* d_in, const int* in_sizes, int n_in,
                              void* d_out, int out_size, void* d_ws, size_t ws_size,
                              hipStream_t stream) {
    const float* input_   = (const float*)d_in[0];   // (B,C,T,1) one-hot fp32
    const float* patterns = (const float*)d_in[1];   // (C,P,1,N) fp32
    float* out = (float*)d_out;                      // (B,N,T,1) fp32

    // Workspace layout: [0, 6144) masks (P*N u32); [8192, 8192+B*T) chars u8
    // (identical to round 1)
    unsigned*      masks = (unsigned*)d_ws;
    unsigned char* chars = (unsigned char*)d_ws + 8192;

    hipLaunchKernelGGL(k_disc, dim3((P_ * N_ + 255) / 256), dim3(256), 0, stream,
                       patterns, masks);
    hipLaunchKernelGGL(k_chars, dim3(B_ * (T_ / 1024)), dim3(256), 0, stream,
                       input_, (unsigned*)chars);
    hipLaunchKernelGGL(k_final, dim3(T_ / 1024, N_, B_), dim3(256), 0, stream,
                       chars, masks, out);
}

// Round 5
// 68.652 us; speedup vs baseline: 2.0302x; 1.1600x over previous
//
#include <hip/hip_runtime.h>

// Problem constants (from reference)
#define B_ 32
#define C_ 32
#define T_ 8192
#define N_ 256
#define P_ 6
#define TV_ (T_ - P_ + 1)   // valid conv length = 8187

// ---------------------------------------------------------------------------
// Kernel 0: discretize patterns -> pre-derived byte-SIMD match tables.
// Layout tabs[n][12]: dwords 0..5 = xs[p] (XOR splat), 6..11 = om[p] (mask).
//   pc==0 (column sum<=0): don't-care         -> om=0
//   pc==1 (unique argmax): must equal req     -> xs=req*0x01010101, om=0x80..
//   pc>=2 (tied argmax):   can never match    -> xs=0x7F7F7F7F,   om=0x80..
// (identical mask computation to round-1/4 k_disc; MKTAB relocated here)
// ---------------------------------------------------------------------------
__global__ void k_disc(const float* __restrict__ pat, unsigned* __restrict__ tabs) {
    int tid = blockIdx.x * blockDim.x + threadIdx.x;
    if (tid >= P_ * N_) return;
    int p = tid / N_;
    int n = tid - p * N_;
    float maxv = -3.402823466e+38f;
    float sum = 0.0f;
    unsigned mask = 0u;
    #pragma unroll
    for (int c = 0; c < C_; ++c) {
        float v = pat[((size_t)c * P_ + p) * N_ + n];
        sum += v;
        if (v > maxv) { maxv = v; mask = (1u << c); }
        else if (v == maxv) { mask |= (1u << c); }
    }
    if (!(sum > 0.0f)) mask = 0u;
    int pc = __popc(mask);
    unsigned req = (unsigned)(__ffs((int)mask) - 1);
    unsigned xs = (pc == 1) ? req * 0x01010101u : 0x7F7F7F7Fu;
    unsigned om = (pc == 0) ? 0u : 0x80808080u;
    tabs[n * 12 + p]     = xs;
    tabs[n * 12 + 6 + p] = om;
}

// ---------------------------------------------------------------------------
// Kernel 1: decode one-hot input (B,C,T,1) -> chars[B][T] (u8 packed in u32).
// (verbatim round-1/4 kernel)
// ---------------------------------------------------------------------------
__global__ void k_chars(const float* __restrict__ inp, unsigned* __restrict__ chars32) {
    int bx = blockIdx.x;                  // [0, B * T/1024)
    int b  = bx >> 3;                     // T/1024 = 8 chunks per batch
    int t  = ((bx & 7) << 10) + (threadIdx.x << 2);
    const float* base = inp + (size_t)b * C_ * T_ + t;
    float ax = 0.f, ay = 0.f, az = 0.f, aw = 0.f;
    #pragma unroll
    for (int c = 0; c < C_; ++c) {
        float4 v = *(const float4*)(base + (size_t)c * T_);
        float fc = (float)c;
        ax += fc * v.x; ay += fc * v.y; az += fc * v.z; aw += fc * v.w;
    }
    unsigned w = ((unsigned)(ax + 0.5f))
               | ((unsigned)(ay + 0.5f) << 8)
               | ((unsigned)(az + 0.5f) << 16)
               | ((unsigned)(aw + 0.5f) << 24);
    chars32[((size_t)b * T_ + t) >> 2] = w;
}

// ---------------------------------------------------------------------------
// Kernel 2: SAME per-n structure as round 4 (LDS chars staging, byte-SIMD
// match, one float4 store per thread per n). ONE change: each block now
// loops over 32 n-values -> grid shrinks 65536 -> 2048 blocks, amortizing
// block setup (stage+barrier+dispatch) 32x. Tables come pre-derived from
// k_disc as 3 contiguous uint4 per n.
// ---------------------------------------------------------------------------
__global__ void k_final(const unsigned char* __restrict__ chars,
                        const unsigned* __restrict__ tabs,
                        float* __restrict__ out) {
    __shared__ unsigned s32[258];         // 1024 chars + 8 halo bytes
    int tc  = blockIdx.x;                 // 0..7
    int ng  = blockIdx.y;                 // 0..7  (group of 32 n)
    int b   = blockIdx.z;                 // 0..31
    int tid = threadIdx.x;
    int t0  = tc << 10;
    int tb  = t0 + (tid << 2);

    const unsigned* csrc = (const unsigned*)(chars + (size_t)b * T_ + t0);
    s32[tid] = csrc[tid];
    if (tid < 2) {
        unsigned v = 0u;
        int gt = t0 + 1024 + tid * 4;     // byte index into chars[b][*]
        if (gt < T_) v = csrc[256 + tid];
        s32[256 + tid] = v;
    }
    __syncthreads();

    unsigned w0 = s32[tid], w1 = s32[tid + 1], w2 = s32[tid + 2];
    unsigned cw0 = w0;
    unsigned cw1 = __builtin_amdgcn_alignbyte(w1, w0, 1);
    unsigned cw2 = __builtin_amdgcn_alignbyte(w1, w0, 2);
    unsigned cw3 = __builtin_amdgcn_alignbyte(w1, w0, 3);
    unsigned cw4 = w1;
    unsigned cw5 = __builtin_amdgcn_alignbyte(w2, w1, 1);

    int n0 = ng << 5;
    const uint4* tp = (const uint4*)tabs + (size_t)n0 * 3;
    float* obase = out + ((size_t)(b * N_ + n0)) * T_ + tb;
    bool tail = (tc == 7) && (tb + 3 >= TV_);

    #pragma unroll 4
    for (int g = 0; g < 32; ++g) {
        uint4 A = tp[g * 3 + 0];          // xs0..xs3
        uint4 Bv = tp[g * 3 + 1];         // xs4, xs5, om0, om1
        uint4 Cv = tp[g * 3 + 2];         // om2..om5

        unsigned orv;
        orv  = ((cw0 ^ A.x)  + 0x7F7F7F7FU) & Bv.z;
        orv |= ((cw1 ^ A.y)  + 0x7F7F7F7FU) & Bv.w;   // v_and_or_b32
        orv |= ((cw2 ^ A.z)  + 0x7F7F7F7FU) & Cv.x;
        orv |= ((cw3 ^ A.w)  + 0x7F7F7F7FU) & Cv.y;
        orv |= ((cw4 ^ Bv.x) + 0x7F7F7F7FU) & Cv.z;
        orv |= ((cw5 ^ Bv.y) + 0x7F7F7F7FU) & Cv.w;

        float res[4];
        #pragma unroll
        for (int j = 0; j < 4; ++j)
            res[j] = (orv & (0x80u << (8 * j))) ? 0.0f : 1.0f;

        if (tail) {                       // only last chunk's tail lanes
            unsigned act = Bv.z | Bv.w | Cv.x | Cv.y | Cv.z | Cv.w;
            float padf = (act == 0u) ? 1.0f : 0.0f;  // psum==0: pad matches
            #pragma unroll
            for (int j = 0; j < 4; ++j)
                if (tb + j >= TV_) res[j] = padf;
        }

        float4 r; r.x = res[0]; r.y = res[1]; r.z = res[2]; r.w = res[3];
        *(float4*)(obase + (size_t)g * T_) = r;
    }
}

// ---------------------------------------------------------------------------
extern "C" void kernel_launch(void* const* d_in, const int* in_sizes, int n_in,
                              void* d_out, int out_size, void* d_ws, size_t ws_size,
                              hipStream_t stream) {
    const float* input_   = (const float*)d_in[0];   // (B,C,T,1) one-hot fp32
    const float* patterns = (const float*)d_in[1];   // (C,P,1,N) fp32
    float* out = (float*)d_out;                      // (B,N,T,1) fp32

    // ws layout: [0, 12288) tabs (N*12 u32); [16384, 16384+256K) chars u8
    unsigned*      tabs  = (unsigned*)d_ws;
    unsigned char* chars = (unsigned char*)d_ws + 16384;

    hipLaunchKernelGGL(k_disc, dim3((P_ * N_ + 255) / 256), dim3(256), 0, stream,
                       patterns, tabs);
    hipLaunchKernelGGL(k_chars, dim3(B_ * (T_ / 1024)), dim3(256), 0, stream,
                       input_, (unsigned*)chars);
    hipLaunchKernelGGL(k_final, dim3(T_ / 1024, N_ / 32, B_), dim3(256), 0, stream,
                       chars, tabs, out);
}